// Round 7
// baseline (859.320 us; speedup 1.0000x reference)
//
#include <hip/hip_runtime.h>
#include <hip/hip_bf16.h>

typedef __attribute__((ext_vector_type(4))) float f32x4;
typedef __attribute__((ext_vector_type(8))) short bf16x8;
typedef __attribute__((ext_vector_type(4))) unsigned short u16x4;

#define NTOK 65536
#define DMODEL 256
#define DFF 1024
#define NH 8
#define HD 32
#define SSP 128
#define TLEN 128
#define SCALE 0.17677669529663687f  /* 1/sqrt(32) */

__device__ __forceinline__ float bf2f(unsigned short u) {
    return __builtin_bit_cast(float, (unsigned int)u << 16);
}
__device__ __forceinline__ unsigned short f2bf(float f) {
    unsigned int u = __builtin_bit_cast(unsigned int, f);
    unsigned int r = u + 0x7fffu + ((u >> 16) & 1u);
    return (unsigned short)(r >> 16);
}
__device__ __forceinline__ void gload_lds16(const void* g, void* l) {
    __builtin_amdgcn_global_load_lds((const __attribute__((address_space(1))) void*)g,
                                     (__attribute__((address_space(3))) void*)l, 16, 0, 0);
}

// ---------------- weight fp32 -> bf16 conversion (all 6 mats, 1,048,576 elems) --------
__global__ __launch_bounds__(256)
void cvt_w(const float* __restrict__ a, const float* __restrict__ b,
           const float* __restrict__ c, const float* __restrict__ d,
           const float* __restrict__ e, const float* __restrict__ f,
           unsigned short* __restrict__ o)
{
    int i = blockIdx.x * 256 + threadIdx.x;
    float v;
    if      (i < 196608)  v = a[i];
    else if (i < 262144)  v = b[i - 196608];
    else if (i < 458752)  v = c[i - 262144];
    else if (i < 524288)  v = d[i - 458752];
    else if (i < 786432)  v = e[i - 524288];
    else                  v = f[i - 786432];
    o[i] = f2bf(v);
}

// ---------------- copy x -> residual (fp32) + rmsnorm -> bf16, one wave per row -------
__global__ __launch_bounds__(256)
void rms_copy(const float* __restrict__ x, const float* __restrict__ g,
              float* __restrict__ xo, unsigned short* __restrict__ xn)
{
    const int row = blockIdx.x * 4 + (threadIdx.x >> 6);
    const int lane = threadIdx.x & 63;
    const float4 v = *(const float4*)&x[(size_t)row * DMODEL + lane * 4];
    float s = v.x * v.x + v.y * v.y + v.z * v.z + v.w * v.w;
    #pragma unroll
    for (int o = 1; o < 64; o <<= 1) s += __shfl_xor(s, o);
    const float rinv = rsqrtf(s * (1.0f / DMODEL) + 1.1920929e-7f);
    *(float4*)&xo[(size_t)row * DMODEL + lane * 4] = v;
    const float4 gv = *(const float4*)&g[lane * 4];
    u16x4 o4;
    o4[0] = f2bf(v.x * rinv * gv.x);
    o4[1] = f2bf(v.y * rinv * gv.y);
    o4[2] = f2bf(v.z * rinv * gv.z);
    o4[3] = f2bf(v.w * rinv * gv.w);
    *(u16x4*)&xn[(size_t)row * DMODEL + lane * 4] = o4;
}

// ---------------- GEMM: C[M,N] = A[M,K] * W[N,K]^T + bias (both bf16 row-major) -------
// BK=64, XOR-swizzled LDS; 1D grid, XCD-bijective swizzle, col-tile fastest.
// EPI 0: bias -> bf16 out; EPI 2: fp32 residual +=
template<int EPI>
__global__ __launch_bounds__(256)
void gemm_bt(const unsigned short* __restrict__ A,
             const unsigned short* __restrict__ W,
             const float* __restrict__ bias,
             unsigned short* __restrict__ Cb,
             float* __restrict__ Cf,
             int N, int K, int NCT)
{
    __shared__ unsigned short lds[17408];    // staging 32KB; epilogue reuse [128][136]
    unsigned short* As = lds;                // [128][64]
    unsigned short* Bs = lds + 8192;         // [128][64]

    const int tid = threadIdx.x;
    const int wave = tid >> 6, lane = tid & 63;
    const int wr = wave >> 1, wc = wave & 1;

    const int nwg = gridDim.x;
    const int bid = blockIdx.x;
    const int lin = (bid & 7) * (nwg >> 3) + (bid >> 3);   // nwg % 8 == 0
    const int row0 = (lin / NCT) * 128;
    const int col0 = (lin % NCT) * 128;

    f32x4 acc[4][4];
    #pragma unroll
    for (int i = 0; i < 4; i++)
        #pragma unroll
        for (int j = 0; j < 4; j++)
            acc[i][j] = (f32x4){0.f, 0.f, 0.f, 0.f};

    const int srow  = tid >> 3;                            // 0..31
    const int kx    = ((tid & 7) * 8) ^ ((srow & 7) * 8);  // swizzled source k-elem

    const int fr = lane & 15, g = lane >> 4;
    const int sw = (fr & 7) * 8;                           // read-side XOR

    for (int k0 = 0; k0 < K; k0 += 64) {
        #pragma unroll
        for (int q = 0; q < 4; q++) {
            const int row = q * 32 + srow;
            gload_lds16(A + (size_t)(row0 + row) * K + k0 + kx, As + q * 2048 + tid * 8);
            gload_lds16(W + (size_t)(col0 + row) * K + k0 + kx, Bs + q * 2048 + tid * 8);
        }
        __syncthreads();
        #pragma unroll
        for (int kh = 0; kh < 2; kh++) {
            const int ke = (kh * 32 + g * 8) ^ sw;
            bf16x8 af[4], bw[4];
            #pragma unroll
            for (int i = 0; i < 4; i++)
                af[i] = *(const bf16x8*)&As[(wr * 64 + i * 16 + fr) * 64 + ke];
            #pragma unroll
            for (int j = 0; j < 4; j++)
                bw[j] = *(const bf16x8*)&Bs[(wc * 64 + j * 16 + fr) * 64 + ke];
            #pragma unroll
            for (int i = 0; i < 4; i++)
                #pragma unroll
                for (int j = 0; j < 4; j++)
                    acc[i][j] = __builtin_amdgcn_mfma_f32_16x16x32_bf16(af[i], bw[j], acc[i][j], 0, 0, 0);
        }
        __syncthreads();
    }

    if constexpr (EPI == 2) {
        #pragma unroll
        for (int i = 0; i < 4; i++) {
            #pragma unroll
            for (int j = 0; j < 4; j++) {
                const int col = col0 + wc * 64 + j * 16 + fr;
                const float bv = bias[col];
                #pragma unroll
                for (int r = 0; r < 4; r++) {
                    const int row = row0 + wr * 64 + i * 16 + g * 4 + r;
                    Cf[(size_t)row * N + col] += acc[i][j][r] + bv;
                }
            }
        }
    } else {
        #pragma unroll
        for (int i = 0; i < 4; i++) {
            #pragma unroll
            for (int j = 0; j < 4; j++) {
                const int col = wc * 64 + j * 16 + fr;
                const float bv = bias[col0 + col];
                #pragma unroll
                for (int r = 0; r < 4; r++) {
                    float v = acc[i][j][r] + bv;
                    lds[(wr * 64 + i * 16 + g * 4 + r) * 136 + col] = f2bf(v);
                }
            }
        }
        __syncthreads();
        #pragma unroll
        for (int q = 0; q < 8; q++) {
            const int chunk = q * 256 + tid;
            const int row = chunk >> 4, c16 = chunk & 15;
            *(bf16x8*)&Cb[(size_t)(row0 + row) * N + col0 + c16 * 8] =
                *(const bf16x8*)&lds[row * 136 + c16 * 8];
        }
    }
}

// ---------------- fused GEMM + residual += + rmsnorm (full-row tile 64x256) -----------
// xo[row] += A*W^T + bias; xn[row] = rmsnorm(xo[row]) * g
__global__ __launch_bounds__(256)
void gemm_rms(const unsigned short* __restrict__ A,
              const unsigned short* __restrict__ W,
              const float* __restrict__ bias,
              float* __restrict__ xo,
              const float* __restrict__ gv,
              unsigned short* __restrict__ xn,
              int K)
{
    __shared__ unsigned short As[64 * 64];    // 8 KB
    __shared__ unsigned short Bs[256 * 64];   // 32 KB
    __shared__ float red[64 * 4];             // per-row per-wave partial sums

    const int tid = threadIdx.x;
    const int wave = tid >> 6, lane = tid & 63;
    const int fr = lane & 15, g4 = lane >> 4;

    const int nwg = gridDim.x;
    const int bid = blockIdx.x;
    const int lin = (bid & 7) * (nwg >> 3) + (bid >> 3);
    const int row0 = lin * 64;

    f32x4 acc[4][4];
    #pragma unroll
    for (int i = 0; i < 4; i++)
        #pragma unroll
        for (int j = 0; j < 4; j++)
            acc[i][j] = (f32x4){0.f, 0.f, 0.f, 0.f};

    const int srow = tid >> 3;
    const int kx   = ((tid & 7) * 8) ^ ((srow & 7) * 8);
    const int sw   = (fr & 7) * 8;

    for (int k0 = 0; k0 < K; k0 += 64) {
        #pragma unroll
        for (int p = 0; p < 2; p++)
            gload_lds16(A + (size_t)(row0 + p * 32 + srow) * K + k0 + kx, As + p * 2048 + tid * 8);
        #pragma unroll
        for (int p = 0; p < 8; p++)
            gload_lds16(W + (size_t)(p * 32 + srow) * K + k0 + kx, Bs + p * 2048 + tid * 8);
        __syncthreads();
        #pragma unroll
        for (int kh = 0; kh < 2; kh++) {
            const int ke = (kh * 32 + g4 * 8) ^ sw;
            bf16x8 af[4], bw[4];
            #pragma unroll
            for (int i = 0; i < 4; i++)
                af[i] = *(const bf16x8*)&As[(i * 16 + fr) * 64 + ke];
            #pragma unroll
            for (int j = 0; j < 4; j++)
                bw[j] = *(const bf16x8*)&Bs[(wave * 64 + j * 16 + fr) * 64 + ke];
            #pragma unroll
            for (int i = 0; i < 4; i++)
                #pragma unroll
                for (int j = 0; j < 4; j++)
                    acc[i][j] = __builtin_amdgcn_mfma_f32_16x16x32_bf16(af[i], bw[j], acc[i][j], 0, 0, 0);
        }
        __syncthreads();
    }

    #pragma unroll
    for (int i = 0; i < 4; i++) {
        #pragma unroll
        for (int j = 0; j < 4; j++) {
            const int col = wave * 64 + j * 16 + fr;
            const float bv = bias[col];
            #pragma unroll
            for (int r = 0; r < 4; r++) {
                const int row = row0 + i * 16 + g4 * 4 + r;
                const float xv = xo[(size_t)row * DMODEL + col] + acc[i][j][r] + bv;
                xo[(size_t)row * DMODEL + col] = xv;
                acc[i][j][r] = xv;
            }
        }
    }
    #pragma unroll
    for (int i = 0; i < 4; i++) {
        #pragma unroll
        for (int r = 0; r < 4; r++) {
            float p = acc[i][0][r] * acc[i][0][r] + acc[i][1][r] * acc[i][1][r]
                    + acc[i][2][r] * acc[i][2][r] + acc[i][3][r] * acc[i][3][r];
            #pragma unroll
            for (int o = 1; o < 16; o <<= 1) p += __shfl_xor(p, o);
            if (fr == 0) red[(i * 16 + g4 * 4 + r) * 4 + wave] = p;
        }
    }
    __syncthreads();
    #pragma unroll
    for (int i = 0; i < 4; i++) {
        #pragma unroll
        for (int r = 0; r < 4; r++) {
            const int rl = i * 16 + g4 * 4 + r;
            const float rsq = red[rl * 4 + 0] + red[rl * 4 + 1] + red[rl * 4 + 2] + red[rl * 4 + 3];
            const float rinv = rsqrtf(rsq * (1.0f / DMODEL) + 1.1920929e-7f);
            #pragma unroll
            for (int j = 0; j < 4; j++) {
                const int col = wave * 64 + j * 16 + fr;
                xn[(size_t)(row0 + rl) * DMODEL + col] = f2bf(acc[i][j][r] * rinv * gv[col]);
            }
        }
    }
}

// ---------------- fused FFN v2: xo += GELU(A*W1^T+b1)*W2^T + b2, 64-row tiles ---------
// Hidden in 8 chunks of 128. Per chunk: 8 uniform phases (4 GEMM1 + 4 GEMM2), each
// staging one 16KB W-tile into double-buffered Bs with issue-early/wait-late prefetch.
// A-fragments load straight from L2 (no As). Hs is WAVE-PRIVATE (wave w owns output
// rows [16w,16w+16)) -> GELU/H hand-off needs no barriers. LDS 49 KB -> 3 blocks/CU.
__global__ __launch_bounds__(256, 3)
void ffn_fused(const unsigned short* __restrict__ A,   // xn [NTOK][256]
               const unsigned short* __restrict__ W1,  // [1024][256] bf16
               const float* __restrict__ b1,
               const unsigned short* __restrict__ W2,  // [256][1024] bf16
               const float* __restrict__ b2,
               float* __restrict__ xo)
{
    __shared__ unsigned short Bs[2][128 * 64];   // 2 x 16 KB
    __shared__ unsigned short Hs[4][16 * 136];   // 17 KB, per-wave (16B-aligned rows)

    const int tid = threadIdx.x;
    const int wave = tid >> 6, lane = tid & 63;
    const int fr = lane & 15, g = lane >> 4;

    const int nwg = gridDim.x, bid = blockIdx.x;
    const int lin = (bid & 7) * (nwg >> 3) + (bid >> 3);
    const int row0 = lin * 64;

    const int srow = tid >> 3;                             // 0..31
    const int kx   = ((tid & 7) * 8) ^ ((srow & 7) * 8);   // source-side XOR (16B chunks)
    const int sw   = (fr & 7) * 8;                         // read-side XOR

    f32x4 acc2[16];
    #pragma unroll
    for (int j = 0; j < 16; j++) acc2[j] = (f32x4){0.f, 0.f, 0.f, 0.f};
    f32x4 acc1[8];

    // phase p = 0..63: chunk c = p>>3, sub s = p&7.
    // s<4 : GEMM1, W1 rows [c*128, +128), k-slice s*64      (row stride 256)
    // s>=4: GEMM2, jg=(s-4)>>1, k0=((s-4)&1)*64,
    //       W2 rows [jg*128, +128), k-slice c*128+k0        (row stride 1024)
    auto stage = [&](int b, int p) {
        const int c = p >> 3, s = p & 7;
        const unsigned short* src;
        int rstride;
        if (s < 4) { src = W1 + (size_t)(c * 128) * DMODEL + s * 64; rstride = DMODEL; }
        else {
            const int jg = (s - 4) >> 1, k0 = ((s - 4) & 1) * 64;
            src = W2 + (size_t)(jg * 128) * DFF + c * 128 + k0; rstride = DFF;
        }
        #pragma unroll
        for (int q = 0; q < 4; q++)
            gload_lds16(src + (size_t)(q * 32 + srow) * rstride + kx,
                        &Bs[b][q * 2048 + tid * 8]);
    };

    stage(0, 0);
    __syncthreads();

    for (int p = 0; p < 64; p++) {
        const int b = p & 1, c = p >> 3, s = p & 7;
        if (p + 1 < 64) stage(b ^ 1, p + 1);      // issue-early: lands during compute
        if (s == 0) {
            #pragma unroll
            for (int j = 0; j < 8; j++) acc1[j] = (f32x4){0.f, 0.f, 0.f, 0.f};
        }
        if (s < 4) {
            // GEMM1: acc1[j] += A-frag x W1-frag ; A from global (L2-hot)
            const int k0 = s * 64;
            #pragma unroll
            for (int kh = 0; kh < 2; kh++) {
                const bf16x8 af = *(const bf16x8*)&A[(size_t)(row0 + wave * 16 + fr) * DMODEL
                                                     + k0 + kh * 32 + g * 8];
                const int ke = (kh * 32 + g * 8) ^ sw;
                #pragma unroll
                for (int j = 0; j < 8; j++) {
                    const bf16x8 bw = *(const bf16x8*)&Bs[b][(j * 16 + fr) * 64 + ke];
                    acc1[j] = __builtin_amdgcn_mfma_f32_16x16x32_bf16(af, bw, acc1[j], 0, 0, 0);
                }
            }
        } else {
            const int jg = (s - 4) >> 1, k0 = ((s - 4) & 1) * 64;
            #pragma unroll
            for (int kh = 0; kh < 2; kh++) {
                const bf16x8 ha = *(const bf16x8*)&Hs[wave][fr * 136 + k0 + kh * 32 + g * 8];
                const int ke = (kh * 32 + g * 8) ^ sw;
                #pragma unroll
                for (int j = 0; j < 8; j++) {
                    const bf16x8 bw = *(const bf16x8*)&Bs[b][(j * 16 + fr) * 64 + ke];
                    acc2[jg * 8 + j] = __builtin_amdgcn_mfma_f32_16x16x32_bf16(ha, bw, acc2[jg * 8 + j], 0, 0, 0);
                }
            }
        }
        if (s == 3) {
            // GELU chunk -> wave-private Hs (no barrier needed: same wave reads it)
            #pragma unroll
            for (int j = 0; j < 8; j++) {
                const float bv = b1[c * 128 + j * 16 + fr];
                #pragma unroll
                for (int r = 0; r < 4; r++) {
                    float v = acc1[j][r] + bv;
                    v = 0.5f * v * (1.0f + erff(v * 0.70710678118654752f));
                    Hs[wave][(g * 4 + r) * 136 + j * 16 + fr] = f2bf(v);
                }
            }
        }
        __syncthreads();   // drains prefetch (had full compute to land) + Bs reuse safety
    }

    // epilogue: fp32 residual RMW
    #pragma unroll
    for (int jg = 0; jg < 2; jg++) {
        #pragma unroll
        for (int j = 0; j < 8; j++) {
            const int col = jg * 128 + j * 16 + fr;
            const float bv = b2[col];
            #pragma unroll
            for (int r = 0; r < 4; r++) {
                const int row = row0 + wave * 16 + g * 4 + r;
                xo[(size_t)row * DMODEL + col] += acc2[jg * 8 + j][r] + bv;
            }
        }
    }
}

// ---------------- spatial attention: one block per (bt, head), 128x128, MFMA ----------
__global__ __launch_bounds__(256)
void attn_spatial(const unsigned short* __restrict__ qkv,  // [NTOK][768]
                  const int* __restrict__ coords,          // [128][2]
                  unsigned short* __restrict__ out)        // [NTOK][256]
{
    __shared__ unsigned short Qs[128 * 32];
    __shared__ unsigned short Ks[128 * 32];
    __shared__ unsigned short Vt[32 * 136];   // V^T, padded rows
    __shared__ unsigned short Pb[64 * 132];   // bf16 P for one 64-row half
    __shared__ int cx[128], cy[128];

    const int bt = blockIdx.x, h = blockIdx.y;
    const int tid = threadIdx.x, wave = tid >> 6, lane = tid & 63;
    const size_t base = (size_t)bt * SSP * 768 + (size_t)h * HD;

    {   // stage Q,K (row-major [128][32]) and V transposed
        const int rr = tid >> 1, cb = (tid & 1) * 16;
        const unsigned short* p = qkv + base + (size_t)rr * 768 + cb;
        *(bf16x8*)&Qs[rr * 32 + cb]     = *(const bf16x8*)p;
        *(bf16x8*)&Qs[rr * 32 + cb + 8] = *(const bf16x8*)(p + 8);
        p += 256;
        *(bf16x8*)&Ks[rr * 32 + cb]     = *(const bf16x8*)p;
        *(bf16x8*)&Ks[rr * 32 + cb + 8] = *(const bf16x8*)(p + 8);
        p += 256;
        bf16x8 v0 = *(const bf16x8*)p, v1 = *(const bf16x8*)(p + 8);
        #pragma unroll
        for (int e = 0; e < 8; e++) {
            Vt[(cb + e) * 136 + rr]     = (unsigned short)v0[e];
            Vt[(cb + 8 + e) * 136 + rr] = (unsigned short)v1[e];
        }
        if (tid < 128) { cx[tid] = coords[2 * tid]; cy[tid] = coords[2 * tid + 1]; }
    }
    __syncthreads();

    const int fr = lane & 15;
    const int g  = lane >> 4;
    const int fko = g * 8;

    for (int half = 0; half < 2; half++) {
        const int rbase = half * 64 + wave * 16;
        bf16x8 aq = *(const bf16x8*)&Qs[(rbase + fr) * 32 + fko];
        f32x4 sc[8];
        #pragma unroll
        for (int tj = 0; tj < 8; tj++) {
            bf16x8 bk = *(const bf16x8*)&Ks[(tj * 16 + fr) * 32 + fko];
            sc[tj] = __builtin_amdgcn_mfma_f32_16x16x32_bf16(aq, bk, (f32x4){0.f,0.f,0.f,0.f}, 0, 0, 0);
        }
        int cxi[4], cyi[4];
        #pragma unroll
        for (int r = 0; r < 4; r++) { const int i = rbase + g * 4 + r; cxi[r] = cx[i]; cyi[r] = cy[i]; }
        float m[4] = {-1e30f, -1e30f, -1e30f, -1e30f};
        #pragma unroll
        for (int tj = 0; tj < 8; tj++) {
            const int j = tj * 16 + fr;
            const int cxj = cx[j], cyj = cy[j];
            #pragma unroll
            for (int r = 0; r < 4; r++) {
                int dx = cxi[r] - cxj; dx = dx < 0 ? -dx : dx;
                int dy = cyi[r] - cyj; dy = dy < 0 ? -dy : dy;
                const float v = ((dx > dy ? dx : dy) > 4) ? -1e9f : sc[tj][r] * SCALE;
                sc[tj][r] = v;
                m[r] = fmaxf(m[r], v);
            }
        }
        #pragma unroll
        for (int r = 0; r < 4; r++) {
            #pragma unroll
            for (int o = 1; o < 16; o <<= 1) m[r] = fmaxf(m[r], __shfl_xor(m[r], o));
        }
        float sm[4] = {0.f, 0.f, 0.f, 0.f};
        #pragma unroll
        for (int tj = 0; tj < 8; tj++) {
            #pragma unroll
            for (int r = 0; r < 4; r++) {
                const float e = __expf(sc[tj][r] - m[r]);
                sc[tj][r] = e;
                sm[r] += e;
            }
        }
        #pragma unroll
        for (int r = 0; r < 4; r++) {
            #pragma unroll
            for (int o = 1; o < 16; o <<= 1) sm[r] += __shfl_xor(sm[r], o);
        }
        float inv[4];
        #pragma unroll
        for (int r = 0; r < 4; r++) inv[r] = 1.0f / sm[r];
        #pragma unroll
        for (int tj = 0; tj < 8; tj++) {
            #pragma unroll
            for (int r = 0; r < 4; r++)
                Pb[(wave * 16 + g * 4 + r) * 132 + tj * 16 + fr] = f2bf(sc[tj][r] * inv[r]);
        }
        #pragma unroll
        for (int td = 0; td < 2; td++) {
            f32x4 o = (f32x4){0.f, 0.f, 0.f, 0.f};
            #pragma unroll
            for (int kk = 0; kk < 4; kk++) {
                bf16x8 pa = *(const bf16x8*)&Pb[(wave * 16 + fr) * 132 + kk * 32 + fko];
                bf16x8 bv = *(const bf16x8*)&Vt[(td * 16 + fr) * 136 + kk * 32 + fko];
                o = __builtin_amdgcn_mfma_f32_16x16x32_bf16(pa, bv, o, 0, 0, 0);
            }
            #pragma unroll
            for (int r = 0; r < 4; r++) {
                const int i = half * 64 + wave * 16 + g * 4 + r;
                const int d = td * 16 + fr;
                out[((size_t)(bt * SSP + i)) * DMODEL + h * HD + d] = f2bf(o[r]);
            }
        }
    }
}

// ---------------- temporal attention: window of <=4 keys, per-thread scalar -----------
__device__ __forceinline__ float dot32(const float* __restrict__ qr,
                                       const unsigned short* __restrict__ Kt, int j)
{
    float a = 0.f;
    #pragma unroll
    for (int d = 0; d < 32; d++) a += qr[d] * bf2f(Kt[d * 128 + j]);
    return a;
}

__global__ __launch_bounds__(128)
void attn_temporal(const unsigned short* __restrict__ qkv,  // [NTOK][768]
                   unsigned short* __restrict__ out)        // [NTOK][256]
{
    __shared__ unsigned short Kt[32 * 128], Vt[32 * 128];   // transposed [d][t]
    const int bs = blockIdx.x, h = blockIdx.y;
    const int b = bs >> 7, sp = bs & 127;
    const int tid = threadIdx.x;   // t index 0..127
    const size_t rb = ((size_t)b * 16384 + (size_t)tid * 128 + sp) * 768 + (size_t)h * HD;
    bf16x8 qreg[4];
    #pragma unroll
    for (int c = 0; c < 4; c++) {
        qreg[c] = *(const bf16x8*)(qkv + rb + c * 8);
        bf16x8 k = *(const bf16x8*)(qkv + rb + 256 + c * 8);
        bf16x8 v = *(const bf16x8*)(qkv + rb + 512 + c * 8);
        #pragma unroll
        for (int e = 0; e < 8; e++) {
            const int d = c * 8 + e;
            Kt[d * 128 + tid] = (unsigned short)k[e];
            Vt[d * 128 + tid] = (unsigned short)v[e];
        }
    }
    __syncthreads();

    const int i = tid;
    float qr[32];
    #pragma unroll
    for (int d = 0; d < 32; d++) qr[d] = bf2f((unsigned short)qreg[d >> 3][d & 7]);

    float s0 = -1e30f, s1 = -1e30f, s2 = -1e30f;
    if (i >= 3) s0 = dot32(qr, Kt, i - 3) * SCALE;
    if (i >= 2) s1 = dot32(qr, Kt, i - 2) * SCALE;
    if (i >= 1) s2 = dot32(qr, Kt, i - 1) * SCALE;
    const float s3 = dot32(qr, Kt, i) * SCALE;

    const float mx = fmaxf(fmaxf(s0, s1), fmaxf(s2, s3));
    const float p0 = __expf(s0 - mx), p1 = __expf(s1 - mx), p2 = __expf(s2 - mx), p3 = __expf(s3 - mx);
    const float inv = 1.0f / (p0 + p1 + p2 + p3);
    const int j0 = i >= 3 ? i - 3 : 0;
    const int j1 = i >= 2 ? i - 2 : 0;
    const int j2 = i >= 1 ? i - 1 : 0;
    const size_t ob = ((size_t)b * 16384 + (size_t)i * 128 + sp) * DMODEL + (size_t)h * HD;
    #pragma unroll
    for (int d = 0; d < 32; d++) {
        const float o = (p0 * bf2f(Vt[d * 128 + j0]) + p1 * bf2f(Vt[d * 128 + j1]) +
                         p2 * bf2f(Vt[d * 128 + j2]) + p3 * bf2f(Vt[d * 128 + i])) * inv;
        out[ob + d] = f2bf(o);
    }
}

// --------------------------------------------------------------------------------------
extern "C" void kernel_launch(void* const* d_in, const int* in_sizes, int n_in,
                              void* d_out, int out_size, void* d_ws, size_t ws_size,
                              hipStream_t stream)
{
    const float* x_in   = (const float*)d_in[0];
    const int*   coords = (const int*)d_in[1];
    const float* Wqkv_s = (const float*)d_in[3];
    const float* bqkv_s = (const float*)d_in[4];
    const float* Wo_s   = (const float*)d_in[5];
    const float* bo_s   = (const float*)d_in[6];
    const float* Wqkv_t = (const float*)d_in[7];
    const float* bqkv_t = (const float*)d_in[8];
    const float* Wo_t   = (const float*)d_in[9];
    const float* bo_t   = (const float*)d_in[10];
    const float* g1     = (const float*)d_in[11];
    const float* g2     = (const float*)d_in[12];
    const float* g3     = (const float*)d_in[13];
    const float* W1     = (const float*)d_in[14];
    const float* b1     = (const float*)d_in[15];
    const float* W2     = (const float*)d_in[16];
    const float* b2     = (const float*)d_in[17];
    float* xo = (float*)d_out;

    char* ws = (char*)d_ws;
    unsigned short* wb  = (unsigned short*)ws;                                 // 2 MB weights
    unsigned short* xn  = (unsigned short*)(ws + (size_t)2 * 1024 * 1024);     // 32 MiB norm / attn-out
    unsigned short* big = (unsigned short*)(ws + (size_t)34 * 1024 * 1024);    // 96 MiB qkv

    unsigned short* wQKVs = wb;
    unsigned short* wOs   = wb + 196608;
    unsigned short* wQKVt = wb + 262144;
    unsigned short* wOt   = wb + 458752;
    unsigned short* w1b   = wb + 524288;
    unsigned short* w2b   = wb + 786432;

    cvt_w<<<4096, 256, 0, stream>>>(Wqkv_s, Wo_s, Wqkv_t, Wo_t, W1, W2, wb);

    // ---- spatial block ----
    rms_copy<<<16384, 256, 0, stream>>>(x_in, g1, xo, xn);
    gemm_bt<0><<<3072, 256, 0, stream>>>(xn, wQKVs, bqkv_s, big, nullptr, 768, 256, 6);
    attn_spatial<<<dim3(512, 8), 256, 0, stream>>>(big, coords, xn);
    gemm_rms<<<1024, 256, 0, stream>>>(xn, wOs, bo_s, xo, g2, xn, 256);

    // ---- temporal block ----
    gemm_bt<0><<<3072, 256, 0, stream>>>(xn, wQKVt, bqkv_t, big, nullptr, 768, 256, 6);
    attn_temporal<<<dim3(512, 8), 128, 0, stream>>>(big, xn);
    gemm_rms<<<1024, 256, 0, stream>>>(xn, wOt, bo_t, xo, g3, xn, 256);

    // ---- fused FFN ----
    ffn_fused<<<1024, 256, 0, stream>>>(xn, w1b, b1, w2b, b2, xo);
}

// Round 8
// 617.803 us; speedup vs baseline: 1.3909x; 1.3909x over previous
//
#include <hip/hip_runtime.h>
#include <hip/hip_bf16.h>

typedef __attribute__((ext_vector_type(4))) float f32x4;
typedef __attribute__((ext_vector_type(8))) short bf16x8;
typedef __attribute__((ext_vector_type(4))) unsigned short u16x4;

#define NTOK 65536
#define DMODEL 256
#define DFF 1024
#define NH 8
#define HD 32
#define SSP 128
#define TLEN 128
#define SCALE 0.17677669529663687f  /* 1/sqrt(32) */

__device__ __forceinline__ float bf2f(unsigned short u) {
    return __builtin_bit_cast(float, (unsigned int)u << 16);
}
__device__ __forceinline__ unsigned short f2bf(float f) {
    unsigned int u = __builtin_bit_cast(unsigned int, f);
    unsigned int r = u + 0x7fffu + ((u >> 16) & 1u);
    return (unsigned short)(r >> 16);
}
__device__ __forceinline__ void gload_lds16(const void* g, void* l) {
    __builtin_amdgcn_global_load_lds((const __attribute__((address_space(1))) void*)g,
                                     (__attribute__((address_space(3))) void*)l, 16, 0, 0);
}

// ---------------- weight fp32 -> bf16 conversion (all 6 mats, 1,048,576 elems) --------
__global__ __launch_bounds__(256)
void cvt_w(const float* __restrict__ a, const float* __restrict__ b,
           const float* __restrict__ c, const float* __restrict__ d,
           const float* __restrict__ e, const float* __restrict__ f,
           unsigned short* __restrict__ o)
{
    int i = blockIdx.x * 256 + threadIdx.x;
    float v;
    if      (i < 196608)  v = a[i];
    else if (i < 262144)  v = b[i - 196608];
    else if (i < 458752)  v = c[i - 262144];
    else if (i < 524288)  v = d[i - 458752];
    else if (i < 786432)  v = e[i - 524288];
    else                  v = f[i - 786432];
    o[i] = f2bf(v);
}

// ---------------- copy x -> residual (fp32) + rmsnorm -> bf16, one wave per row -------
__global__ __launch_bounds__(256)
void rms_copy(const float* __restrict__ x, const float* __restrict__ g,
              float* __restrict__ xo, unsigned short* __restrict__ xn)
{
    const int row = blockIdx.x * 4 + (threadIdx.x >> 6);
    const int lane = threadIdx.x & 63;
    const float4 v = *(const float4*)&x[(size_t)row * DMODEL + lane * 4];
    float s = v.x * v.x + v.y * v.y + v.z * v.z + v.w * v.w;
    #pragma unroll
    for (int o = 1; o < 64; o <<= 1) s += __shfl_xor(s, o);
    const float rinv = rsqrtf(s * (1.0f / DMODEL) + 1.1920929e-7f);
    *(float4*)&xo[(size_t)row * DMODEL + lane * 4] = v;
    const float4 gv = *(const float4*)&g[lane * 4];
    u16x4 o4;
    o4[0] = f2bf(v.x * rinv * gv.x);
    o4[1] = f2bf(v.y * rinv * gv.y);
    o4[2] = f2bf(v.z * rinv * gv.z);
    o4[3] = f2bf(v.w * rinv * gv.w);
    *(u16x4*)&xn[(size_t)row * DMODEL + lane * 4] = o4;
}

// ---------------- GEMM: C[M,N] = A[M,K] * W[N,K]^T + bias (both bf16 row-major) -------
// BK=64, XOR-swizzled LDS; 1D grid, XCD-bijective swizzle, col-tile fastest.
// EPI 0: bias -> bf16 out; EPI 2: fp32 residual +=
template<int EPI>
__global__ __launch_bounds__(256)
void gemm_bt(const unsigned short* __restrict__ A,
             const unsigned short* __restrict__ W,
             const float* __restrict__ bias,
             unsigned short* __restrict__ Cb,
             float* __restrict__ Cf,
             int N, int K, int NCT)
{
    __shared__ unsigned short lds[17408];    // staging 32KB; epilogue reuse [128][136]
    unsigned short* As = lds;                // [128][64]
    unsigned short* Bs = lds + 8192;         // [128][64]

    const int tid = threadIdx.x;
    const int wave = tid >> 6, lane = tid & 63;
    const int wr = wave >> 1, wc = wave & 1;

    const int nwg = gridDim.x;
    const int bid = blockIdx.x;
    const int lin = (bid & 7) * (nwg >> 3) + (bid >> 3);   // nwg % 8 == 0
    const int row0 = (lin / NCT) * 128;
    const int col0 = (lin % NCT) * 128;

    f32x4 acc[4][4];
    #pragma unroll
    for (int i = 0; i < 4; i++)
        #pragma unroll
        for (int j = 0; j < 4; j++)
            acc[i][j] = (f32x4){0.f, 0.f, 0.f, 0.f};

    const int srow  = tid >> 3;                            // 0..31
    const int kx    = ((tid & 7) * 8) ^ ((srow & 7) * 8);  // swizzled source k-elem

    const int fr = lane & 15, g = lane >> 4;
    const int sw = (fr & 7) * 8;                           // read-side XOR

    for (int k0 = 0; k0 < K; k0 += 64) {
        #pragma unroll
        for (int q = 0; q < 4; q++) {
            const int row = q * 32 + srow;
            gload_lds16(A + (size_t)(row0 + row) * K + k0 + kx, As + q * 2048 + tid * 8);
            gload_lds16(W + (size_t)(col0 + row) * K + k0 + kx, Bs + q * 2048 + tid * 8);
        }
        __syncthreads();
        #pragma unroll
        for (int kh = 0; kh < 2; kh++) {
            const int ke = (kh * 32 + g * 8) ^ sw;
            bf16x8 af[4], bw[4];
            #pragma unroll
            for (int i = 0; i < 4; i++)
                af[i] = *(const bf16x8*)&As[(wr * 64 + i * 16 + fr) * 64 + ke];
            #pragma unroll
            for (int j = 0; j < 4; j++)
                bw[j] = *(const bf16x8*)&Bs[(wc * 64 + j * 16 + fr) * 64 + ke];
            #pragma unroll
            for (int i = 0; i < 4; i++)
                #pragma unroll
                for (int j = 0; j < 4; j++)
                    acc[i][j] = __builtin_amdgcn_mfma_f32_16x16x32_bf16(af[i], bw[j], acc[i][j], 0, 0, 0);
        }
        __syncthreads();
    }

    if constexpr (EPI == 2) {
        #pragma unroll
        for (int i = 0; i < 4; i++) {
            #pragma unroll
            for (int j = 0; j < 4; j++) {
                const int col = col0 + wc * 64 + j * 16 + fr;
                const float bv = bias[col];
                #pragma unroll
                for (int r = 0; r < 4; r++) {
                    const int row = row0 + wr * 64 + i * 16 + g * 4 + r;
                    Cf[(size_t)row * N + col] += acc[i][j][r] + bv;
                }
            }
        }
    } else {
        #pragma unroll
        for (int i = 0; i < 4; i++) {
            #pragma unroll
            for (int j = 0; j < 4; j++) {
                const int col = wc * 64 + j * 16 + fr;
                const float bv = bias[col0 + col];
                #pragma unroll
                for (int r = 0; r < 4; r++) {
                    float v = acc[i][j][r] + bv;
                    lds[(wr * 64 + i * 16 + g * 4 + r) * 136 + col] = f2bf(v);
                }
            }
        }
        __syncthreads();
        #pragma unroll
        for (int q = 0; q < 8; q++) {
            const int chunk = q * 256 + tid;
            const int row = chunk >> 4, c16 = chunk & 15;
            *(bf16x8*)&Cb[(size_t)(row0 + row) * N + col0 + c16 * 8] =
                *(const bf16x8*)&lds[row * 136 + c16 * 8];
        }
    }
}

// ---------------- fused GEMM + residual += + rmsnorm (full-row tile 64x256) -----------
// xo[row] += A*W^T + bias; xn[row] = rmsnorm(xo[row]) * g
__global__ __launch_bounds__(256)
void gemm_rms(const unsigned short* __restrict__ A,
              const unsigned short* __restrict__ W,
              const float* __restrict__ bias,
              float* __restrict__ xo,
              const float* __restrict__ gv,
              unsigned short* __restrict__ xn,
              int K)
{
    __shared__ unsigned short As[64 * 64];    // 8 KB
    __shared__ unsigned short Bs[256 * 64];   // 32 KB
    __shared__ float red[64 * 4];             // per-row per-wave partial sums

    const int tid = threadIdx.x;
    const int wave = tid >> 6, lane = tid & 63;
    const int fr = lane & 15, g4 = lane >> 4;

    const int nwg = gridDim.x;
    const int bid = blockIdx.x;
    const int lin = (bid & 7) * (nwg >> 3) + (bid >> 3);
    const int row0 = lin * 64;

    f32x4 acc[4][4];
    #pragma unroll
    for (int i = 0; i < 4; i++)
        #pragma unroll
        for (int j = 0; j < 4; j++)
            acc[i][j] = (f32x4){0.f, 0.f, 0.f, 0.f};

    const int srow = tid >> 3;
    const int kx   = ((tid & 7) * 8) ^ ((srow & 7) * 8);
    const int sw   = (fr & 7) * 8;

    for (int k0 = 0; k0 < K; k0 += 64) {
        #pragma unroll
        for (int p = 0; p < 2; p++)
            gload_lds16(A + (size_t)(row0 + p * 32 + srow) * K + k0 + kx, As + p * 2048 + tid * 8);
        #pragma unroll
        for (int p = 0; p < 8; p++)
            gload_lds16(W + (size_t)(p * 32 + srow) * K + k0 + kx, Bs + p * 2048 + tid * 8);
        __syncthreads();
        #pragma unroll
        for (int kh = 0; kh < 2; kh++) {
            const int ke = (kh * 32 + g4 * 8) ^ sw;
            bf16x8 af[4], bw[4];
            #pragma unroll
            for (int i = 0; i < 4; i++)
                af[i] = *(const bf16x8*)&As[(i * 16 + fr) * 64 + ke];
            #pragma unroll
            for (int j = 0; j < 4; j++)
                bw[j] = *(const bf16x8*)&Bs[(wave * 64 + j * 16 + fr) * 64 + ke];
            #pragma unroll
            for (int i = 0; i < 4; i++)
                #pragma unroll
                for (int j = 0; j < 4; j++)
                    acc[i][j] = __builtin_amdgcn_mfma_f32_16x16x32_bf16(af[i], bw[j], acc[i][j], 0, 0, 0);
        }
        __syncthreads();
    }

    #pragma unroll
    for (int i = 0; i < 4; i++) {
        #pragma unroll
        for (int j = 0; j < 4; j++) {
            const int col = wave * 64 + j * 16 + fr;
            const float bv = bias[col];
            #pragma unroll
            for (int r = 0; r < 4; r++) {
                const int row = row0 + i * 16 + g4 * 4 + r;
                const float xv = xo[(size_t)row * DMODEL + col] + acc[i][j][r] + bv;
                xo[(size_t)row * DMODEL + col] = xv;
                acc[i][j][r] = xv;
            }
        }
    }
    #pragma unroll
    for (int i = 0; i < 4; i++) {
        #pragma unroll
        for (int r = 0; r < 4; r++) {
            float p = acc[i][0][r] * acc[i][0][r] + acc[i][1][r] * acc[i][1][r]
                    + acc[i][2][r] * acc[i][2][r] + acc[i][3][r] * acc[i][3][r];
            #pragma unroll
            for (int o = 1; o < 16; o <<= 1) p += __shfl_xor(p, o);
            if (fr == 0) red[(i * 16 + g4 * 4 + r) * 4 + wave] = p;
        }
    }
    __syncthreads();
    #pragma unroll
    for (int i = 0; i < 4; i++) {
        #pragma unroll
        for (int r = 0; r < 4; r++) {
            const int rl = i * 16 + g4 * 4 + r;
            const float rsq = red[rl * 4 + 0] + red[rl * 4 + 1] + red[rl * 4 + 2] + red[rl * 4 + 3];
            const float rinv = rsqrtf(rsq * (1.0f / DMODEL) + 1.1920929e-7f);
            #pragma unroll
            for (int j = 0; j < 4; j++) {
                const int col = wave * 64 + j * 16 + fr;
                xn[(size_t)(row0 + rl) * DMODEL + col] = f2bf(acc[i][j][r] * rinv * gv[col]);
            }
        }
    }
}

// ---------------- fused FFN v3: xo += GELU(A*W1^T+b1)*W2^T + b2, 64-row tiles ---------
// Same schedule as v2 but the 8 sub-phases are UNROLLED (s compile-time) so all
// accumulator indices are static -> registers, not scratch (rule #20 fix for R7).
__global__ __launch_bounds__(256, 3)
void ffn_fused(const unsigned short* __restrict__ A,   // xn [NTOK][256]
               const unsigned short* __restrict__ W1,  // [1024][256] bf16
               const float* __restrict__ b1,
               const unsigned short* __restrict__ W2,  // [256][1024] bf16
               const float* __restrict__ b2,
               float* __restrict__ xo)
{
    __shared__ unsigned short Bs[2][128 * 64];   // 2 x 16 KB
    __shared__ unsigned short Hs[4][16 * 136];   // 17 KB, per-wave (16B-aligned rows)

    const int tid = threadIdx.x;
    const int wave = tid >> 6, lane = tid & 63;
    const int fr = lane & 15, g = lane >> 4;

    const int nwg = gridDim.x, bid = blockIdx.x;
    const int lin = (bid & 7) * (nwg >> 3) + (bid >> 3);
    const int row0 = lin * 64;

    const int srow = tid >> 3;                             // 0..31
    const int kx   = ((tid & 7) * 8) ^ ((srow & 7) * 8);   // source-side XOR (16B chunks)
    const int sw   = (fr & 7) * 8;                         // read-side XOR

    f32x4 acc2[16];
    #pragma unroll
    for (int j = 0; j < 16; j++) acc2[j] = (f32x4){0.f, 0.f, 0.f, 0.f};
    f32x4 acc1[8];

    // stage phase (c,s) into buffer b. s<4: GEMM1 W1-slice; s>=4: GEMM2 W2-slice.
    auto stage = [&](int b, int c, int s) {
        const unsigned short* src;
        int rstride;
        if (s < 4) { src = W1 + (size_t)(c * 128) * DMODEL + s * 64; rstride = DMODEL; }
        else {
            const int jg = (s - 4) >> 1, k0 = ((s - 4) & 1) * 64;
            src = W2 + (size_t)(jg * 128) * DFF + c * 128 + k0; rstride = DFF;
        }
        #pragma unroll
        for (int q = 0; q < 4; q++)
            gload_lds16(src + (size_t)(q * 32 + srow) * rstride + kx,
                        &Bs[b][q * 2048 + tid * 8]);
    };

    stage(0, 0, 0);
    __syncthreads();

    for (int c = 0; c < 8; c++) {
        #pragma unroll
        for (int s = 0; s < 8; s++) {              // s is COMPILE-TIME after unroll
            const int b = s & 1;
            // issue-early prefetch of next phase
            if (s < 7)           stage(b ^ 1, c, s + 1);
            else if (c + 1 < 8)  stage(b ^ 1, c + 1, 0);
            if (s == 0) {
                #pragma unroll
                for (int j = 0; j < 8; j++) acc1[j] = (f32x4){0.f, 0.f, 0.f, 0.f};
            }
            if (s < 4) {
                const int k0 = s * 64;
                #pragma unroll
                for (int kh = 0; kh < 2; kh++) {
                    const bf16x8 af = *(const bf16x8*)&A[(size_t)(row0 + wave * 16 + fr) * DMODEL
                                                         + k0 + kh * 32 + g * 8];
                    const int ke = (kh * 32 + g * 8) ^ sw;
                    #pragma unroll
                    for (int j = 0; j < 8; j++) {
                        const bf16x8 bw = *(const bf16x8*)&Bs[b][(j * 16 + fr) * 64 + ke];
                        acc1[j] = __builtin_amdgcn_mfma_f32_16x16x32_bf16(af, bw, acc1[j], 0, 0, 0);
                    }
                }
            } else {
                const int jg = (s - 4) >> 1, k0 = ((s - 4) & 1) * 64;
                #pragma unroll
                for (int kh = 0; kh < 2; kh++) {
                    const bf16x8 ha = *(const bf16x8*)&Hs[wave][fr * 136 + k0 + kh * 32 + g * 8];
                    const int ke = (kh * 32 + g * 8) ^ sw;
                    #pragma unroll
                    for (int j = 0; j < 8; j++) {
                        const bf16x8 bw = *(const bf16x8*)&Bs[b][(j * 16 + fr) * 64 + ke];
                        acc2[jg * 8 + j] = __builtin_amdgcn_mfma_f32_16x16x32_bf16(ha, bw, acc2[jg * 8 + j], 0, 0, 0);
                    }
                }
            }
            if (s == 3) {
                // GELU chunk -> wave-private Hs (same wave consumes; DS in-order)
                #pragma unroll
                for (int j = 0; j < 8; j++) {
                    const float bv = b1[c * 128 + j * 16 + fr];
                    #pragma unroll
                    for (int r = 0; r < 4; r++) {
                        float v = acc1[j][r] + bv;
                        v = 0.5f * v * (1.0f + erff(v * 0.70710678118654752f));
                        Hs[wave][(g * 4 + r) * 136 + j * 16 + fr] = f2bf(v);
                    }
                }
            }
            __syncthreads();   // prefetch landed under compute; Bs reuse safety
        }
    }

    // epilogue: fp32 residual RMW
    #pragma unroll
    for (int jg = 0; jg < 2; jg++) {
        #pragma unroll
        for (int j = 0; j < 8; j++) {
            const int col = jg * 128 + j * 16 + fr;
            const float bv = b2[col];
            #pragma unroll
            for (int r = 0; r < 4; r++) {
                const int row = row0 + wave * 16 + g * 4 + r;
                xo[(size_t)row * DMODEL + col] += acc2[jg * 8 + j][r] + bv;
            }
        }
    }
}

// ---------------- spatial attention: one block per (bt, head), 128x128, MFMA ----------
__global__ __launch_bounds__(256)
void attn_spatial(const unsigned short* __restrict__ qkv,  // [NTOK][768]
                  const int* __restrict__ coords,          // [128][2]
                  unsigned short* __restrict__ out)        // [NTOK][256]
{
    __shared__ unsigned short Qs[128 * 32];
    __shared__ unsigned short Ks[128 * 32];
    __shared__ unsigned short Vt[32 * 136];   // V^T, padded rows
    __shared__ unsigned short Pb[64 * 132];   // bf16 P for one 64-row half
    __shared__ int cx[128], cy[128];

    const int bt = blockIdx.x, h = blockIdx.y;
    const int tid = threadIdx.x, wave = tid >> 6, lane = tid & 63;
    const size_t base = (size_t)bt * SSP * 768 + (size_t)h * HD;

    {   // stage Q,K (row-major [128][32]) and V transposed
        const int rr = tid >> 1, cb = (tid & 1) * 16;
        const unsigned short* p = qkv + base + (size_t)rr * 768 + cb;
        *(bf16x8*)&Qs[rr * 32 + cb]     = *(const bf16x8*)p;
        *(bf16x8*)&Qs[rr * 32 + cb + 8] = *(const bf16x8*)(p + 8);
        p += 256;
        *(bf16x8*)&Ks[rr * 32 + cb]     = *(const bf16x8*)p;
        *(bf16x8*)&Ks[rr * 32 + cb + 8] = *(const bf16x8*)(p + 8);
        p += 256;
        bf16x8 v0 = *(const bf16x8*)p, v1 = *(const bf16x8*)(p + 8);
        #pragma unroll
        for (int e = 0; e < 8; e++) {
            Vt[(cb + e) * 136 + rr]     = (unsigned short)v0[e];
            Vt[(cb + 8 + e) * 136 + rr] = (unsigned short)v1[e];
        }
        if (tid < 128) { cx[tid] = coords[2 * tid]; cy[tid] = coords[2 * tid + 1]; }
    }
    __syncthreads();

    const int fr = lane & 15;
    const int g  = lane >> 4;
    const int fko = g * 8;

    for (int half = 0; half < 2; half++) {
        const int rbase = half * 64 + wave * 16;
        bf16x8 aq = *(const bf16x8*)&Qs[(rbase + fr) * 32 + fko];
        f32x4 sc[8];
        #pragma unroll
        for (int tj = 0; tj < 8; tj++) {
            bf16x8 bk = *(const bf16x8*)&Ks[(tj * 16 + fr) * 32 + fko];
            sc[tj] = __builtin_amdgcn_mfma_f32_16x16x32_bf16(aq, bk, (f32x4){0.f,0.f,0.f,0.f}, 0, 0, 0);
        }
        int cxi[4], cyi[4];
        #pragma unroll
        for (int r = 0; r < 4; r++) { const int i = rbase + g * 4 + r; cxi[r] = cx[i]; cyi[r] = cy[i]; }
        float m[4] = {-1e30f, -1e30f, -1e30f, -1e30f};
        #pragma unroll
        for (int tj = 0; tj < 8; tj++) {
            const int j = tj * 16 + fr;
            const int cxj = cx[j], cyj = cy[j];
            #pragma unroll
            for (int r = 0; r < 4; r++) {
                int dx = cxi[r] - cxj; dx = dx < 0 ? -dx : dx;
                int dy = cyi[r] - cyj; dy = dy < 0 ? -dy : dy;
                const float v = ((dx > dy ? dx : dy) > 4) ? -1e9f : sc[tj][r] * SCALE;
                sc[tj][r] = v;
                m[r] = fmaxf(m[r], v);
            }
        }
        #pragma unroll
        for (int r = 0; r < 4; r++) {
            #pragma unroll
            for (int o = 1; o < 16; o <<= 1) m[r] = fmaxf(m[r], __shfl_xor(m[r], o));
        }
        float sm[4] = {0.f, 0.f, 0.f, 0.f};
        #pragma unroll
        for (int tj = 0; tj < 8; tj++) {
            #pragma unroll
            for (int r = 0; r < 4; r++) {
                const float e = __expf(sc[tj][r] - m[r]);
                sc[tj][r] = e;
                sm[r] += e;
            }
        }
        #pragma unroll
        for (int r = 0; r < 4; r++) {
            #pragma unroll
            for (int o = 1; o < 16; o <<= 1) sm[r] += __shfl_xor(sm[r], o);
        }
        float inv[4];
        #pragma unroll
        for (int r = 0; r < 4; r++) inv[r] = 1.0f / sm[r];
        #pragma unroll
        for (int tj = 0; tj < 8; tj++) {
            #pragma unroll
            for (int r = 0; r < 4; r++)
                Pb[(wave * 16 + g * 4 + r) * 132 + tj * 16 + fr] = f2bf(sc[tj][r] * inv[r]);
        }
        #pragma unroll
        for (int td = 0; td < 2; td++) {
            f32x4 o = (f32x4){0.f, 0.f, 0.f, 0.f};
            #pragma unroll
            for (int kk = 0; kk < 4; kk++) {
                bf16x8 pa = *(const bf16x8*)&Pb[(wave * 16 + fr) * 132 + kk * 32 + fko];
                bf16x8 bv = *(const bf16x8*)&Vt[(td * 16 + fr) * 136 + kk * 32 + fko];
                o = __builtin_amdgcn_mfma_f32_16x16x32_bf16(pa, bv, o, 0, 0, 0);
            }
            #pragma unroll
            for (int r = 0; r < 4; r++) {
                const int i = half * 64 + wave * 16 + g * 4 + r;
                const int d = td * 16 + fr;
                out[((size_t)(bt * SSP + i)) * DMODEL + h * HD + d] = f2bf(o[r]);
            }
        }
    }
}

// ---------------- temporal attention: window of <=4 keys, per-thread scalar -----------
__device__ __forceinline__ float dot32(const float* __restrict__ qr,
                                       const unsigned short* __restrict__ Kt, int j)
{
    float a = 0.f;
    #pragma unroll
    for (int d = 0; d < 32; d++) a += qr[d] * bf2f(Kt[d * 128 + j]);
    return a;
}

__global__ __launch_bounds__(128)
void attn_temporal(const unsigned short* __restrict__ qkv,  // [NTOK][768]
                   unsigned short* __restrict__ out)        // [NTOK][256]
{
    __shared__ unsigned short Kt[32 * 128], Vt[32 * 128];   // transposed [d][t]
    const int bs = blockIdx.x, h = blockIdx.y;
    const int b = bs >> 7, sp = bs & 127;
    const int tid = threadIdx.x;   // t index 0..127
    const size_t rb = ((size_t)b * 16384 + (size_t)tid * 128 + sp) * 768 + (size_t)h * HD;
    bf16x8 qreg[4];
    #pragma unroll
    for (int c = 0; c < 4; c++) {
        qreg[c] = *(const bf16x8*)(qkv + rb + c * 8);
        bf16x8 k = *(const bf16x8*)(qkv + rb + 256 + c * 8);
        bf16x8 v = *(const bf16x8*)(qkv + rb + 512 + c * 8);
        #pragma unroll
        for (int e = 0; e < 8; e++) {
            const int d = c * 8 + e;
            Kt[d * 128 + tid] = (unsigned short)k[e];
            Vt[d * 128 + tid] = (unsigned short)v[e];
        }
    }
    __syncthreads();

    const int i = tid;
    float qr[32];
    #pragma unroll
    for (int d = 0; d < 32; d++) qr[d] = bf2f((unsigned short)qreg[d >> 3][d & 7]);

    float s0 = -1e30f, s1 = -1e30f, s2 = -1e30f;
    if (i >= 3) s0 = dot32(qr, Kt, i - 3) * SCALE;
    if (i >= 2) s1 = dot32(qr, Kt, i - 2) * SCALE;
    if (i >= 1) s2 = dot32(qr, Kt, i - 1) * SCALE;
    const float s3 = dot32(qr, Kt, i) * SCALE;

    const float mx = fmaxf(fmaxf(s0, s1), fmaxf(s2, s3));
    const float p0 = __expf(s0 - mx), p1 = __expf(s1 - mx), p2 = __expf(s2 - mx), p3 = __expf(s3 - mx);
    const float inv = 1.0f / (p0 + p1 + p2 + p3);
    const int j0 = i >= 3 ? i - 3 : 0;
    const int j1 = i >= 2 ? i - 2 : 0;
    const int j2 = i >= 1 ? i - 1 : 0;
    const size_t ob = ((size_t)b * 16384 + (size_t)i * 128 + sp) * DMODEL + (size_t)h * HD;
    #pragma unroll
    for (int d = 0; d < 32; d++) {
        const float o = (p0 * bf2f(Vt[d * 128 + j0]) + p1 * bf2f(Vt[d * 128 + j1]) +
                         p2 * bf2f(Vt[d * 128 + j2]) + p3 * bf2f(Vt[d * 128 + i])) * inv;
        out[ob + d] = f2bf(o);
    }
}

// --------------------------------------------------------------------------------------
extern "C" void kernel_launch(void* const* d_in, const int* in_sizes, int n_in,
                              void* d_out, int out_size, void* d_ws, size_t ws_size,
                              hipStream_t stream)
{
    const float* x_in   = (const float*)d_in[0];
    const int*   coords = (const int*)d_in[1];
    const float* Wqkv_s = (const float*)d_in[3];
    const float* bqkv_s = (const float*)d_in[4];
    const float* Wo_s   = (const float*)d_in[5];
    const float* bo_s   = (const float*)d_in[6];
    const float* Wqkv_t = (const float*)d_in[7];
    const float* bqkv_t = (const float*)d_in[8];
    const float* Wo_t   = (const float*)d_in[9];
    const float* bo_t   = (const float*)d_in[10];
    const float* g1     = (const float*)d_in[11];
    const float* g2     = (const float*)d_in[12];
    const float* g3     = (const float*)d_in[13];
    const float* W1     = (const float*)d_in[14];
    const float* b1     = (const float*)d_in[15];
    const float* W2     = (const float*)d_in[16];
    const float* b2     = (const float*)d_in[17];
    float* xo = (float*)d_out;

    char* ws = (char*)d_ws;
    unsigned short* wb  = (unsigned short*)ws;                                 // 2 MB weights
    unsigned short* xn  = (unsigned short*)(ws + (size_t)2 * 1024 * 1024);     // 32 MiB norm / attn-out
    unsigned short* big = (unsigned short*)(ws + (size_t)34 * 1024 * 1024);    // 96 MiB qkv

    unsigned short* wQKVs = wb;
    unsigned short* wOs   = wb + 196608;
    unsigned short* wQKVt = wb + 262144;
    unsigned short* wOt   = wb + 458752;
    unsigned short* w1b   = wb + 524288;
    unsigned short* w2b   = wb + 786432;

    cvt_w<<<4096, 256, 0, stream>>>(Wqkv_s, Wo_s, Wqkv_t, Wo_t, W1, W2, wb);

    // ---- spatial block ----
    rms_copy<<<16384, 256, 0, stream>>>(x_in, g1, xo, xn);
    gemm_bt<0><<<3072, 256, 0, stream>>>(xn, wQKVs, bqkv_s, big, nullptr, 768, 256, 6);
    attn_spatial<<<dim3(512, 8), 256, 0, stream>>>(big, coords, xn);
    gemm_rms<<<1024, 256, 0, stream>>>(xn, wOs, bo_s, xo, g2, xn, 256);

    // ---- temporal block ----
    gemm_bt<0><<<3072, 256, 0, stream>>>(xn, wQKVt, bqkv_t, big, nullptr, 768, 256, 6);
    attn_temporal<<<dim3(512, 8), 128, 0, stream>>>(big, xn);
    gemm_rms<<<1024, 256, 0, stream>>>(xn, wOt, bo_t, xo, g3, xn, 256);

    // ---- fused FFN ----
    ffn_fused<<<1024, 256, 0, stream>>>(xn, w1b, b1, w2b, b2, xo);
}